// Round 7
// baseline (109.890 us; speedup 1.0000x reference)
//
#include <hip/hip_runtime.h>
#include <hip/hip_bf16.h>

typedef __bf16 bf16x8 __attribute__((ext_vector_type(8)));
typedef float  f32x4  __attribute__((ext_vector_type(4)));

// freqs[i] = 10000^(-i/16) = 10^(-i/4), i=0..7 (odd k-chunks scale by 1e-2)
__constant__ __device__ const float FREQ8[8] = {
    1.0f, 0.5623413251903491f, 0.31622776601683794f, 0.17782794100389228f,
    0.1f, 0.05623413251903491f, 0.031622776601683794f, 0.017782794100389228f };

// Persistent blocks + chunk-level software pipeline.
// Key: issue chunk c+1's input LOADS before chunk c's STORES, so the
// compiler's s_waitcnt for load data (vmcnt counts loads+stores IN ORDER)
// never drains outstanding stores inside the loop. Stores stay in flight
// continuously, like the 6.7 TB/s fill kernel.
// MFMA mapping (per R3/R5): A-frag=W (row=lane&15->e), B-frag=emb
// (col=lane&15->point), D: col->point, 4 consecutive e per lane -> dwordx4.
// Plain stores (nontemporal = 2x slower, R4). No LDS.
template<bool POW2>
__global__ __launch_bounds__(256, 4) void relds_mfma(
    const float* __restrict__ pos,   // [B,N,3]
    const float* __restrict__ tim,   // [B,N]
    const float* __restrict__ W,     // [32,32] row-major W[e][d]
    const float* __restrict__ bias,  // [32]
    float* __restrict__ out_attn,    // f32 [P,32]
    float* __restrict__ out_emb,     // f32 [P,32]
    int N, int NN, int P, int logN, int nchunks, int cpb)
{
    const int tid  = threadIdx.x;
    const int lane = tid & 63;
    const int wave = tid >> 6;
    const int row  = lane & 15;   // point-slot in B/D cols; e-row for A frag
    const int kb   = lane >> 4;   // k-chunk 0..3; also e-quad for D rows

    const int c0 = blockIdx.x * cpb;
    if (c0 >= nchunks) return;
    const int c1 = (c0 + cpb < nchunks) ? (c0 + cpb) : nchunks;

    // ---- A fragments (W) + bias quads, once per persistent block ----
    bf16x8 Wf[2];
    f32x4  bq[2];
    #pragma unroll
    for (int n = 0; n < 2; ++n) {
        const int e = n * 16 + row;
        const float4 wA = *reinterpret_cast<const float4*>(W + e * 32 + kb * 8);
        const float4 wB = *reinterpret_cast<const float4*>(W + e * 32 + kb * 8 + 4);
        Wf[n][0] = (__bf16)wA.x; Wf[n][1] = (__bf16)wA.y;
        Wf[n][2] = (__bf16)wA.z; Wf[n][3] = (__bf16)wA.w;
        Wf[n][4] = (__bf16)wB.x; Wf[n][5] = (__bf16)wB.y;
        Wf[n][6] = (__bf16)wB.z; Wf[n][7] = (__bf16)wB.w;
        const float4 bb = *reinterpret_cast<const float4*>(bias + n * 16 + kb * 4);
        bq[n][0] = bb.x; bq[n][1] = bb.y; bq[n][2] = bb.z; bq[n][3] = bb.w;
    }

    constexpr float INV2PI = 0.15915494309189535f;
    const float premul = INV2PI * ((kb & 1) ? 0.01f : 1.0f);
    const float qoff   = (kb >= 2) ? 0.25f : 0.0f;   // cos(z) = sin(z + 1/4 rev)

    float A[4][8], Bb[4][8];   // double-buffered raw inputs; static indexing only

#define LOADC(chunk, buf) { \
    const int _qb = (chunk) * 256 + wave * 64 + row; \
    _Pragma("unroll") \
    for (int t = 0; t < 4; ++t) { \
        const int q  = _qb + t * 16; \
        const int qc = (q < P) ? q : (P - 1); \
        int in_n, in_m; \
        if (POW2) { \
            in_n = qc >> logN; \
            in_m = ((qc >> (2 * logN)) << logN) | (qc & (N - 1)); \
        } else { \
            const int b_ = qc / NN; const int r_ = qc - b_ * NN; \
            const int n_ = r_ / N;  const int m_ = r_ - n_ * N; \
            in_n = b_ * N + n_;     in_m = b_ * N + m_; \
        } \
        buf[t][0] = pos[in_n * 3 + 0]; buf[t][1] = pos[in_n * 3 + 1]; \
        buf[t][2] = pos[in_n * 3 + 2]; buf[t][3] = pos[in_m * 3 + 0]; \
        buf[t][4] = pos[in_m * 3 + 1]; buf[t][5] = pos[in_m * 3 + 2]; \
        buf[t][6] = tim[in_n];         buf[t][7] = tim[in_m]; \
    } }

#define PROCC(chunk, buf) { \
    const int _qb = (chunk) * 256 + wave * 64 + row; \
    _Pragma("unroll") \
    for (int t = 0; t < 4; ++t) { \
        const int q = _qb + t * 16; \
        const float dx = buf[t][0] - buf[t][3]; \
        const float dy = buf[t][1] - buf[t][4]; \
        const float dz = buf[t][2] - buf[t][5]; \
        const float dt = (buf[t][6] - buf[t][7]) * 18.0f; \
        const float ds2 = dx * dx + dy * dy + dz * dz - dt * dt; \
        const float d   = copysignf(sqrtf(fabsf(ds2)), ds2); \
        const float x   = 1024.0f * fminf(4.0f, fmaxf(-4.0f, d)); \
        const float xr  = x * premul; \
        float v[8]; \
        _Pragma("unroll") \
        for (int j = 0; j < 8; ++j) { \
            float rr = fmaf(xr, FREQ8[j], qoff); \
            rr -= floorf(rr); \
            v[j] = __builtin_amdgcn_sinf(rr); \
        } \
        if (q < P) { \
            float* ep = out_emb + (size_t)q * 32 + kb * 8; \
            f32x4 e0 = { v[0], v[1], v[2], v[3] }; \
            f32x4 e1 = { v[4], v[5], v[6], v[7] }; \
            reinterpret_cast<f32x4*>(ep)[0] = e0; \
            reinterpret_cast<f32x4*>(ep)[1] = e1; \
        } \
        bf16x8 Af; \
        _Pragma("unroll") \
        for (int j = 0; j < 8; ++j) Af[j] = (__bf16)v[j]; \
        f32x4 a0 = __builtin_amdgcn_mfma_f32_16x16x32_bf16(Wf[0], Af, bq[0], 0, 0, 0); \
        f32x4 a1 = __builtin_amdgcn_mfma_f32_16x16x32_bf16(Wf[1], Af, bq[1], 0, 0, 0); \
        if (q < P) { \
            float* ap = out_attn + (size_t)q * 32 + kb * 4; \
            *reinterpret_cast<f32x4*>(ap)      = a0; \
            *reinterpret_cast<f32x4*>(ap + 16) = a1; \
        } \
    } }

    LOADC(c0, A)
    for (int c = c0; c < c1; c += 2) {
        if (c + 1 < c1) LOADC(c + 1, Bb)   // next loads BEFORE current stores
        PROCC(c, A)                        // waits only on A-loads; S(c) issued here
        if (c + 2 < c1) LOADC(c + 2, A)    // prefetch before S(c+1)
        if (c + 1 < c1) PROCC(c + 1, Bb)
    }
#undef LOADC
#undef PROCC
}

extern "C" void kernel_launch(void* const* d_in, const int* in_sizes, int n_in,
                              void* d_out, int out_size, void* d_ws, size_t ws_size,
                              hipStream_t stream) {
    const float* pos  = (const float*)d_in[0];
    const float* tim  = (const float*)d_in[1];
    const float* W    = (const float*)d_in[2];
    const float* bias = (const float*)d_in[3];

    const int BN = in_sizes[1];          // B*N
    const int P  = out_size / 64;        // B*N*N
    const int N  = P / BN;
    const int NN = N * N;

    int logN = 0;
    while ((1 << logN) < N) ++logN;
    const bool pow2 = ((1 << logN) == N);

    float* out_attn = (float*)d_out;
    float* out_emb  = out_attn + (size_t)out_size / 2;

    const int nchunks = (P + 255) / 256;
    const int grid    = 1024;                        // 4 blocks/CU resident
    const int cpb     = (nchunks + grid - 1) / grid; // chunks per block

    if (pow2)
        relds_mfma<true><<<grid, 256, 0, stream>>>(pos, tim, W, bias, out_attn, out_emb, N, NN, P, logN, nchunks, cpb);
    else
        relds_mfma<false><<<grid, 256, 0, stream>>>(pos, tim, W, bias, out_attn, out_emb, N, NN, P, logN, nchunks, cpb);
}

// Round 8
// 108.435 us; speedup vs baseline: 1.0134x; 1.0134x over previous
//
#include <hip/hip_runtime.h>
#include <hip/hip_bf16.h>

typedef __bf16 bf16x8 __attribute__((ext_vector_type(8)));
typedef float  f32x4  __attribute__((ext_vector_type(4)));

// freqs[i] = 10000^(-i/16) = 10^(-i/4), i=0..7 (odd k-chunks scale by 1e-2)
__constant__ __device__ const float FREQ8[8] = {
    1.0f, 0.5623413251903491f, 0.31622776601683794f, 0.17782794100389228f,
    0.1f, 0.05623413251903491f, 0.031622776601683794f, 0.017782794100389228f };

// One wave = 64 points, per-t processing (R6 structure, 107.6us).
// MFMA: A-frag=W (row=lane&15->e), B-frag=emb (col=lane&15->point),
// D: col->point, 4 consecutive e per lane -> dwordx4 attn store (dense:
// covers full 64B segments).
// THIS ROUND: emb stores made dense too. The natural emb store from the
// B-frag layout writes 16B of every 32B per instruction (half-masked 64B
// segments -> ~2x bus cost for 268MB). Fix: ds_bpermute redistributes the
// f32x4 chunks so lane l stores chunk c=l&7 of point p=8X+(l>>3) at a
// contiguous per-instruction 1KB range. Bitwise-identical values.
// Plain stores (nontemporal = 2x slower, R4). No LDS.
template<bool POW2>
__global__ __launch_bounds__(256, 5) void relds_mfma(
    const float* __restrict__ pos,   // [B,N,3]
    const float* __restrict__ tim,   // [B,N]
    const float* __restrict__ W,     // [32,32] row-major W[e][d]
    const float* __restrict__ bias,  // [32]
    float* __restrict__ out_attn,    // f32 [P,32]
    float* __restrict__ out_emb,     // f32 [P,32]
    int N, int NN, int P, int logN)
{
    const int tid  = threadIdx.x;
    const int lane = tid & 63;
    const int wave = tid >> 6;
    const int row  = lane & 15;   // point-slot in B/D cols; e-row for A frag
    const int kb   = lane >> 4;   // k-chunk 0..3; also e-quad for D rows

    // ---- A fragments (W) + bias quads, once per block; L1/L2-resident ----
    bf16x8 Wf[2];
    f32x4  bq[2];
    #pragma unroll
    for (int n = 0; n < 2; ++n) {
        const int e = n * 16 + row;
        const float4 wA = *reinterpret_cast<const float4*>(W + e * 32 + kb * 8);
        const float4 wB = *reinterpret_cast<const float4*>(W + e * 32 + kb * 8 + 4);
        Wf[n][0] = (__bf16)wA.x; Wf[n][1] = (__bf16)wA.y;
        Wf[n][2] = (__bf16)wA.z; Wf[n][3] = (__bf16)wA.w;
        Wf[n][4] = (__bf16)wB.x; Wf[n][5] = (__bf16)wB.y;
        Wf[n][6] = (__bf16)wB.z; Wf[n][7] = (__bf16)wB.w;
        const float4 bb = *reinterpret_cast<const float4*>(bias + n * 16 + kb * 4);
        bq[n][0] = bb.x; bq[n][1] = bb.y; bq[n][2] = bb.z; bq[n][3] = bb.w;
    }

    const int wbase = blockIdx.x * 256 + wave * 64;
    if (wbase >= P) return;

    // lane-uniform angle constants: d = kb*8+j; odd chunk -> freqs*1e-2; kb>=2 -> cos
    constexpr float INV2PI = 0.15915494309189535f;
    const float premul = INV2PI * ((kb & 1) ? 0.01f : 1.0f);
    const float qoff   = (kb >= 2) ? 0.25f : 0.0f;   // cos(z) = sin(z + 1/4 rev)

    // bpermute source-lane byte-addresses for the dense emb store:
    // lane l stores chunk c=l&7 of point p=8X+(l>>3); source lane holds it at
    // s = 16*(c>>1) + p, register e0 if c even else e1.
    const int bp0 = (((lane >> 1) & 3) * 16 + (lane >> 3)) * 4;      // X=0
    const int bp1 = bp0 + 8 * 4;                                     // X=1 (p+=8)
    const bool oddc = (lane & 1);

    #pragma unroll
    for (int t = 0; t < 4; ++t) {
        const int qb_t = wbase + t * 16;      // wave-uniform tile base
        const int q  = qb_t + row;
        const int qc = (q < P) ? q : (P - 1);
        int in_n, in_m;
        if (POW2) {
            in_n = qc >> logN;
            in_m = ((qc >> (2 * logN)) << logN) | (qc & (N - 1));
        } else {
            const int b_ = qc / NN; const int r_ = qc - b_ * NN;
            const int n_ = r_ / N;  const int m_ = r_ - n_ * N;
            in_n = b_ * N + n_;     in_m = b_ * N + m_;
        }
        const float dx = pos[in_n * 3 + 0] - pos[in_m * 3 + 0];
        const float dy = pos[in_n * 3 + 1] - pos[in_m * 3 + 1];
        const float dz = pos[in_n * 3 + 2] - pos[in_m * 3 + 2];
        const float dt = (tim[in_n] - tim[in_m]) * 18.0f;  // TIME_SCALE
        const float ds2 = dx * dx + dy * dy + dz * dz - dt * dt;
        const float d   = copysignf(sqrtf(fabsf(ds2)), ds2);
        const float x   = 1024.0f * fminf(4.0f, fmaxf(-4.0f, d));
        const float xr  = x * premul;   // revolutions, pre-scaled per k-chunk

        float v[8];
        #pragma unroll
        for (int j = 0; j < 8; ++j) {
            float rr = fmaf(xr, FREQ8[j], qoff);
            rr -= floorf(rr);
            v[j] = __builtin_amdgcn_sinf(rr);
        }

        // ---- emb out ----
        if (qb_t + 15 < P) {
            // dense path: redistribute chunks across lanes, 2x contiguous 1KB stores
            #pragma unroll
            for (int X = 0; X < 2; ++X) {
                const int bp = X ? bp1 : bp0;
                f32x4 ov;
                #pragma unroll
                for (int i = 0; i < 4; ++i) {
                    const int a = __builtin_amdgcn_ds_bpermute(bp, __float_as_int(v[i]));
                    const int b = __builtin_amdgcn_ds_bpermute(bp, __float_as_int(v[4 + i]));
                    ov[i] = __int_as_float(oddc ? b : a);
                }
                *reinterpret_cast<f32x4*>(out_emb + (size_t)qb_t * 32 + X * 256 + lane * 4) = ov;
            }
        } else if (q < P) {
            // tail fallback: per-lane strided (rare)
            float* ep = out_emb + (size_t)q * 32 + kb * 8;
            f32x4 e0 = { v[0], v[1], v[2], v[3] };
            f32x4 e1 = { v[4], v[5], v[6], v[7] };
            reinterpret_cast<f32x4*>(ep)[0] = e0;
            reinterpret_cast<f32x4*>(ep)[1] = e1;
        }

        bf16x8 Af;
        #pragma unroll
        for (int j = 0; j < 8; ++j) Af[j] = (__bf16)v[j];
        f32x4 acc0 = __builtin_amdgcn_mfma_f32_16x16x32_bf16(Wf[0], Af, bq[0], 0, 0, 0);
        f32x4 acc1 = __builtin_amdgcn_mfma_f32_16x16x32_bf16(Wf[1], Af, bq[1], 0, 0, 0);

        // ---- attn out: already dense (full 64B segments per instruction) ----
        if (q < P) {
            float* ap = out_attn + (size_t)q * 32 + kb * 4;
            *reinterpret_cast<f32x4*>(ap)      = acc0;  // e = kb*4 .. +3
            *reinterpret_cast<f32x4*>(ap + 16) = acc1;  // e = 16 + kb*4 .. +3
        }
    }
}

extern "C" void kernel_launch(void* const* d_in, const int* in_sizes, int n_in,
                              void* d_out, int out_size, void* d_ws, size_t ws_size,
                              hipStream_t stream) {
    const float* pos  = (const float*)d_in[0];
    const float* tim  = (const float*)d_in[1];
    const float* W    = (const float*)d_in[2];
    const float* bias = (const float*)d_in[3];

    const int BN = in_sizes[1];          // B*N
    const int P  = out_size / 64;        // B*N*N
    const int N  = P / BN;
    const int NN = N * N;

    int logN = 0;
    while ((1 << logN) < N) ++logN;
    const bool pow2 = ((1 << logN) == N);

    float* out_attn = (float*)d_out;
    float* out_emb  = out_attn + (size_t)out_size / 2;

    const int grid = (P + 255) / 256;
    if (pow2)
        relds_mfma<true><<<grid, 256, 0, stream>>>(pos, tim, W, bias, out_attn, out_emb, N, NN, P, logN);
    else
        relds_mfma<false><<<grid, 256, 0, stream>>>(pos, tim, W, bias, out_attn, out_emb, N, NN, P, logN);
}

// Round 9
// 98.240 us; speedup vs baseline: 1.1186x; 1.1038x over previous
//
#include <hip/hip_runtime.h>
#include <hip/hip_bf16.h>

typedef __bf16 bf16x8 __attribute__((ext_vector_type(8)));
typedef float  f32x4  __attribute__((ext_vector_type(4)));

// freqs[i] = 10000^(-i/16) = 10^(-i/4), i=0..7 (odd k-chunks scale by 1e-2)
__constant__ __device__ const float FREQ8[8] = {
    1.0f, 0.5623413251903491f, 0.31622776601683794f, 0.17782794100389228f,
    0.1f, 0.05623413251903491f, 0.031622776601683794f, 0.017782794100389228f };

// DISCRIMINATING PROBE (R9): block-level output specialization.
// Even blocks: sin -> MFMA -> attn stores ONLY. Odd blocks: sin -> emb ONLY.
// Each wave now writes a single contiguous output stream (and under
// round-robin XCD dispatch the two streams use disjoint XCD sets).
// Sin computed twice (~+8us VALU chip-wide, hidden). Same total HBM bytes.
// Tests: dual-stream write interference vs fixed-floor/roofline.
// MFMA mapping (R3/R5): A-frag=W (row=lane&15->e), B-frag=emb
// (col=lane&15->point), D: col->point, 4 consecutive e per lane -> dwordx4.
// Plain stores (nontemporal = 2x slower, R4). No LDS.
template<bool POW2>
__global__ __launch_bounds__(256, 5) void relds_split(
    const float* __restrict__ pos,   // [B,N,3]
    const float* __restrict__ tim,   // [B,N]
    const float* __restrict__ W,     // [32,32] row-major W[e][d]
    const float* __restrict__ bias,  // [32]
    float* __restrict__ out_attn,    // f32 [P,32]
    float* __restrict__ out_emb,     // f32 [P,32]
    int N, int NN, int P, int logN)
{
    const int tid  = threadIdx.x;
    const int lane = tid & 63;
    const int wave = tid >> 6;
    const int row  = lane & 15;   // point-slot in B/D cols; e-row for A frag
    const int kb   = lane >> 4;   // k-chunk 0..3; also e-quad for D rows

    const int side = blockIdx.x & 1;          // 0 = attn, 1 = emb
    const int pid  = blockIdx.x >> 1;
    const int wbase = pid * 256 + wave * 64;
    if (wbase >= P) return;

    // lane-uniform angle constants: d = kb*8+j; odd chunk -> freqs*1e-2; kb>=2 -> cos
    constexpr float INV2PI = 0.15915494309189535f;
    const float premul = INV2PI * ((kb & 1) ? 0.01f : 1.0f);
    const float qoff   = (kb >= 2) ? 0.25f : 0.0f;   // cos(z) = sin(z + 1/4 rev)

    if (side == 0) {
        // ---- A fragments (W) + bias quads; L1/L2-resident ----
        bf16x8 Wf[2];
        f32x4  bq[2];
        #pragma unroll
        for (int n = 0; n < 2; ++n) {
            const int e = n * 16 + row;
            const float4 wA = *reinterpret_cast<const float4*>(W + e * 32 + kb * 8);
            const float4 wB = *reinterpret_cast<const float4*>(W + e * 32 + kb * 8 + 4);
            Wf[n][0] = (__bf16)wA.x; Wf[n][1] = (__bf16)wA.y;
            Wf[n][2] = (__bf16)wA.z; Wf[n][3] = (__bf16)wA.w;
            Wf[n][4] = (__bf16)wB.x; Wf[n][5] = (__bf16)wB.y;
            Wf[n][6] = (__bf16)wB.z; Wf[n][7] = (__bf16)wB.w;
            const float4 bb = *reinterpret_cast<const float4*>(bias + n * 16 + kb * 4);
            bq[n][0] = bb.x; bq[n][1] = bb.y; bq[n][2] = bb.z; bq[n][3] = bb.w;
        }

        #pragma unroll
        for (int t = 0; t < 4; ++t) {
            const int q  = wbase + t * 16 + row;
            const int qc = (q < P) ? q : (P - 1);
            int in_n, in_m;
            if (POW2) {
                in_n = qc >> logN;
                in_m = ((qc >> (2 * logN)) << logN) | (qc & (N - 1));
            } else {
                const int b_ = qc / NN; const int r_ = qc - b_ * NN;
                const int n_ = r_ / N;  const int m_ = r_ - n_ * N;
                in_n = b_ * N + n_;     in_m = b_ * N + m_;
            }
            const float dx = pos[in_n * 3 + 0] - pos[in_m * 3 + 0];
            const float dy = pos[in_n * 3 + 1] - pos[in_m * 3 + 1];
            const float dz = pos[in_n * 3 + 2] - pos[in_m * 3 + 2];
            const float dt = (tim[in_n] - tim[in_m]) * 18.0f;  // TIME_SCALE
            const float ds2 = dx * dx + dy * dy + dz * dz - dt * dt;
            const float d   = copysignf(sqrtf(fabsf(ds2)), ds2);
            const float x   = 1024.0f * fminf(4.0f, fmaxf(-4.0f, d));
            const float xr  = x * premul;

            bf16x8 Af;
            #pragma unroll
            for (int j = 0; j < 8; ++j) {
                float rr = fmaf(xr, FREQ8[j], qoff);
                rr -= floorf(rr);
                Af[j] = (__bf16)__builtin_amdgcn_sinf(rr);
            }
            f32x4 acc0 = __builtin_amdgcn_mfma_f32_16x16x32_bf16(Wf[0], Af, bq[0], 0, 0, 0);
            f32x4 acc1 = __builtin_amdgcn_mfma_f32_16x16x32_bf16(Wf[1], Af, bq[1], 0, 0, 0);

            if (q < P) {
                float* ap = out_attn + (size_t)q * 32 + kb * 4;
                *reinterpret_cast<f32x4*>(ap)      = acc0;  // e = kb*4 .. +3
                *reinterpret_cast<f32x4*>(ap + 16) = acc1;  // e = 16 + kb*4 .. +3
            }
        }
    } else {
        #pragma unroll
        for (int t = 0; t < 4; ++t) {
            const int q  = wbase + t * 16 + row;
            const int qc = (q < P) ? q : (P - 1);
            int in_n, in_m;
            if (POW2) {
                in_n = qc >> logN;
                in_m = ((qc >> (2 * logN)) << logN) | (qc & (N - 1));
            } else {
                const int b_ = qc / NN; const int r_ = qc - b_ * NN;
                const int n_ = r_ / N;  const int m_ = r_ - n_ * N;
                in_n = b_ * N + n_;     in_m = b_ * N + m_;
            }
            const float dx = pos[in_n * 3 + 0] - pos[in_m * 3 + 0];
            const float dy = pos[in_n * 3 + 1] - pos[in_m * 3 + 1];
            const float dz = pos[in_n * 3 + 2] - pos[in_m * 3 + 2];
            const float dt = (tim[in_n] - tim[in_m]) * 18.0f;
            const float ds2 = dx * dx + dy * dy + dz * dz - dt * dt;
            const float d   = copysignf(sqrtf(fabsf(ds2)), ds2);
            const float x   = 1024.0f * fminf(4.0f, fmaxf(-4.0f, d));
            const float xr  = x * premul;

            float v[8];
            #pragma unroll
            for (int j = 0; j < 8; ++j) {
                float rr = fmaf(xr, FREQ8[j], qoff);
                rr -= floorf(rr);
                v[j] = __builtin_amdgcn_sinf(rr);
            }

            if (q < P) {  // lane owns dims kb*8..kb*8+7 of point q
                float* ep = out_emb + (size_t)q * 32 + kb * 8;
                f32x4 e0 = { v[0], v[1], v[2], v[3] };
                f32x4 e1 = { v[4], v[5], v[6], v[7] };
                reinterpret_cast<f32x4*>(ep)[0] = e0;
                reinterpret_cast<f32x4*>(ep)[1] = e1;
            }
        }
    }
}

extern "C" void kernel_launch(void* const* d_in, const int* in_sizes, int n_in,
                              void* d_out, int out_size, void* d_ws, size_t ws_size,
                              hipStream_t stream) {
    const float* pos  = (const float*)d_in[0];
    const float* tim  = (const float*)d_in[1];
    const float* W    = (const float*)d_in[2];
    const float* bias = (const float*)d_in[3];

    const int BN = in_sizes[1];          // B*N
    const int P  = out_size / 64;        // B*N*N
    const int N  = P / BN;
    const int NN = N * N;

    int logN = 0;
    while ((1 << logN) < N) ++logN;
    const bool pow2 = ((1 << logN) == N);

    float* out_attn = (float*)d_out;
    float* out_emb  = out_attn + (size_t)out_size / 2;

    const int grid = 2 * ((P + 255) / 256);   // even blocks: attn, odd: emb
    if (pow2)
        relds_split<true><<<grid, 256, 0, stream>>>(pos, tim, W, bias, out_attn, out_emb, N, NN, P, logN);
    else
        relds_split<false><<<grid, 256, 0, stream>>>(pos, tim, W, bias, out_attn, out_emb, N, NN, P, logN);
}

// Round 10
// 95.187 us; speedup vs baseline: 1.1545x; 1.0321x over previous
//
#include <hip/hip_runtime.h>
#include <hip/hip_bf16.h>

typedef __bf16 bf16x8 __attribute__((ext_vector_type(8)));
typedef float  f32x4  __attribute__((ext_vector_type(4)));

// freqs[i] = 10000^(-i/16) = 10^(-i/4), i=0..7 (odd k-chunks scale by 1e-2)
__constant__ __device__ const float FREQ8[8] = {
    1.0f, 0.5623413251903491f, 0.31622776601683794f, 0.17782794100389228f,
    0.1f, 0.05623413251903491f, 0.031622776601683794f, 0.017782794100389228f };

// R10: PHASE-SEPARATED output specialization (single change vs R9's win).
// R9 (even/odd block split, one stream per wave): 108.4 -> 98.2us, confirming
// dual-stream write interference. But both streams still ran CONCURRENTLY.
// Now: first nblk blocks write attn only, second nblk write emb only. With
// in-order dispatch, ~80% of runtime has exactly ONE active write stream
// (the fill kernel's 6.7 TB/s pattern); only the transition window mixes.
// MFMA mapping (R3/R5): A-frag=W (row=lane&15->e), B-frag=emb
// (col=lane&15->point), D: col->point, 4 consecutive e per lane -> dwordx4.
// Plain stores (nontemporal = 2x slower, R4). No LDS.
template<bool POW2>
__global__ __launch_bounds__(256, 5) void relds_split(
    const float* __restrict__ pos,   // [B,N,3]
    const float* __restrict__ tim,   // [B,N]
    const float* __restrict__ W,     // [32,32] row-major W[e][d]
    const float* __restrict__ bias,  // [32]
    float* __restrict__ out_attn,    // f32 [P,32]
    float* __restrict__ out_emb,     // f32 [P,32]
    int N, int NN, int P, int logN, int nblk)
{
    const int tid  = threadIdx.x;
    const int lane = tid & 63;
    const int wave = tid >> 6;
    const int row  = lane & 15;   // point-slot in B/D cols; e-row for A frag
    const int kb   = lane >> 4;   // k-chunk 0..3; also e-quad for D rows

    const int side = (blockIdx.x >= (unsigned)nblk) ? 1 : 0;  // 0 = attn, 1 = emb
    const int pid  = blockIdx.x - side * nblk;
    const int wbase = pid * 256 + wave * 64;
    if (wbase >= P) return;

    // lane-uniform angle constants: d = kb*8+j; odd chunk -> freqs*1e-2; kb>=2 -> cos
    constexpr float INV2PI = 0.15915494309189535f;
    const float premul = INV2PI * ((kb & 1) ? 0.01f : 1.0f);
    const float qoff   = (kb >= 2) ? 0.25f : 0.0f;   // cos(z) = sin(z + 1/4 rev)

    if (side == 0) {
        // ---- A fragments (W) + bias quads; L1/L2-resident ----
        bf16x8 Wf[2];
        f32x4  bq[2];
        #pragma unroll
        for (int n = 0; n < 2; ++n) {
            const int e = n * 16 + row;
            const float4 wA = *reinterpret_cast<const float4*>(W + e * 32 + kb * 8);
            const float4 wB = *reinterpret_cast<const float4*>(W + e * 32 + kb * 8 + 4);
            Wf[n][0] = (__bf16)wA.x; Wf[n][1] = (__bf16)wA.y;
            Wf[n][2] = (__bf16)wA.z; Wf[n][3] = (__bf16)wA.w;
            Wf[n][4] = (__bf16)wB.x; Wf[n][5] = (__bf16)wB.y;
            Wf[n][6] = (__bf16)wB.z; Wf[n][7] = (__bf16)wB.w;
            const float4 bb = *reinterpret_cast<const float4*>(bias + n * 16 + kb * 4);
            bq[n][0] = bb.x; bq[n][1] = bb.y; bq[n][2] = bb.z; bq[n][3] = bb.w;
        }

        #pragma unroll
        for (int t = 0; t < 4; ++t) {
            const int q  = wbase + t * 16 + row;
            const int qc = (q < P) ? q : (P - 1);
            int in_n, in_m;
            if (POW2) {
                in_n = qc >> logN;
                in_m = ((qc >> (2 * logN)) << logN) | (qc & (N - 1));
            } else {
                const int b_ = qc / NN; const int r_ = qc - b_ * NN;
                const int n_ = r_ / N;  const int m_ = r_ - n_ * N;
                in_n = b_ * N + n_;     in_m = b_ * N + m_;
            }
            const float dx = pos[in_n * 3 + 0] - pos[in_m * 3 + 0];
            const float dy = pos[in_n * 3 + 1] - pos[in_m * 3 + 1];
            const float dz = pos[in_n * 3 + 2] - pos[in_m * 3 + 2];
            const float dt = (tim[in_n] - tim[in_m]) * 18.0f;  // TIME_SCALE
            const float ds2 = dx * dx + dy * dy + dz * dz - dt * dt;
            const float d   = copysignf(sqrtf(fabsf(ds2)), ds2);
            const float x   = 1024.0f * fminf(4.0f, fmaxf(-4.0f, d));
            const float xr  = x * premul;

            bf16x8 Af;
            #pragma unroll
            for (int j = 0; j < 8; ++j) {
                float rr = fmaf(xr, FREQ8[j], qoff);
                rr -= floorf(rr);
                Af[j] = (__bf16)__builtin_amdgcn_sinf(rr);
            }
            f32x4 acc0 = __builtin_amdgcn_mfma_f32_16x16x32_bf16(Wf[0], Af, bq[0], 0, 0, 0);
            f32x4 acc1 = __builtin_amdgcn_mfma_f32_16x16x32_bf16(Wf[1], Af, bq[1], 0, 0, 0);

            if (q < P) {
                float* ap = out_attn + (size_t)q * 32 + kb * 4;
                *reinterpret_cast<f32x4*>(ap)      = acc0;  // e = kb*4 .. +3
                *reinterpret_cast<f32x4*>(ap + 16) = acc1;  // e = 16 + kb*4 .. +3
            }
        }
    } else {
        #pragma unroll
        for (int t = 0; t < 4; ++t) {
            const int q  = wbase + t * 16 + row;
            const int qc = (q < P) ? q : (P - 1);
            int in_n, in_m;
            if (POW2) {
                in_n = qc >> logN;
                in_m = ((qc >> (2 * logN)) << logN) | (qc & (N - 1));
            } else {
                const int b_ = qc / NN; const int r_ = qc - b_ * NN;
                const int n_ = r_ / N;  const int m_ = r_ - n_ * N;
                in_n = b_ * N + n_;     in_m = b_ * N + m_;
            }
            const float dx = pos[in_n * 3 + 0] - pos[in_m * 3 + 0];
            const float dy = pos[in_n * 3 + 1] - pos[in_m * 3 + 1];
            const float dz = pos[in_n * 3 + 2] - pos[in_m * 3 + 2];
            const float dt = (tim[in_n] - tim[in_m]) * 18.0f;
            const float ds2 = dx * dx + dy * dy + dz * dz - dt * dt;
            const float d   = copysignf(sqrtf(fabsf(ds2)), ds2);
            const float x   = 1024.0f * fminf(4.0f, fmaxf(-4.0f, d));
            const float xr  = x * premul;

            float v[8];
            #pragma unroll
            for (int j = 0; j < 8; ++j) {
                float rr = fmaf(xr, FREQ8[j], qoff);
                rr -= floorf(rr);
                v[j] = __builtin_amdgcn_sinf(rr);
            }

            if (q < P) {  // lane owns dims kb*8..kb*8+7 of point q
                float* ep = out_emb + (size_t)q * 32 + kb * 8;
                f32x4 e0 = { v[0], v[1], v[2], v[3] };
                f32x4 e1 = { v[4], v[5], v[6], v[7] };
                reinterpret_cast<f32x4*>(ep)[0] = e0;
                reinterpret_cast<f32x4*>(ep)[1] = e1;
            }
        }
    }
}

extern "C" void kernel_launch(void* const* d_in, const int* in_sizes, int n_in,
                              void* d_out, int out_size, void* d_ws, size_t ws_size,
                              hipStream_t stream) {
    const float* pos  = (const float*)d_in[0];
    const float* tim  = (const float*)d_in[1];
    const float* W    = (const float*)d_in[2];
    const float* bias = (const float*)d_in[3];

    const int BN = in_sizes[1];          // B*N
    const int P  = out_size / 64;        // B*N*N
    const int N  = P / BN;
    const int NN = N * N;

    int logN = 0;
    while ((1 << logN) < N) ++logN;
    const bool pow2 = ((1 << logN) == N);

    float* out_attn = (float*)d_out;
    float* out_emb  = out_attn + (size_t)out_size / 2;

    const int nblk = (P + 255) / 256;
    const int grid = 2 * nblk;           // blocks [0,nblk): attn, [nblk,2nblk): emb
    if (pow2)
        relds_split<true><<<grid, 256, 0, stream>>>(pos, tim, W, bias, out_attn, out_emb, N, NN, P, logN, nblk);
    else
        relds_split<false><<<grid, 256, 0, stream>>>(pos, tim, W, bias, out_attn, out_emb, N, NN, P, logN, nblk);
}